// Round 6
// baseline (180.397 us; speedup 1.0000x reference)
//
#include <hip/hip_runtime.h>
#include <hip/hip_fp16.h>
#include <math.h>

// HieraFormer fused block, split-phase version:
//   transpose -> MFMA QKV proj -> qk_k (z=QK^T fp16 to global) ->
//   tau_k (entmax tau, wave-private Newton) -> pv_k (k-split, software-pipelined) -> LN.
// B=2, D_MODEL=384, H=3, D_K=128, N=2048.
#define DM   384
#define NH   3
#define DK   128
#define NSEQ 2048
#define BATCH 2
#define NTOK (BATCH*NSEQ)      // 4096
#define SEG  (BATCH*NSEQ*DM)   // 1572864 elements
#define NEWTON_IT 8
#define KSPLIT 2
#define KHALF (NSEQ/KSPLIT)    // 1024

typedef __attribute__((ext_vector_type(8))) short     bf16x8;
typedef __attribute__((ext_vector_type(4))) float     f32x4;
typedef __attribute__((ext_vector_type(8))) _Float16  h8;
typedef __attribute__((ext_vector_type(2))) _Float16  h2v;

#if __has_builtin(__builtin_amdgcn_fdot2)
#define HAVE_FDOT2 1
#else
#define HAVE_FDOT2 0
#endif

__device__ __forceinline__ unsigned short f2bf(float f) {
  unsigned u = __builtin_bit_cast(unsigned, f);
  u += 0x7FFFu + ((u >> 16) & 1u);          // RNE
  return (unsigned short)(u >> 16);
}

// ---------------------------------------------------------------- transpose
__global__ __launch_bounds__(256) void transpose_k(const float* __restrict__ x,
                                                   float* __restrict__ xT,
                                                   unsigned short* __restrict__ xbf) {
  __shared__ float tile[32][33];
  int b  = blockIdx.z;
  int cB = blockIdx.y * 32;
  int nB = blockIdx.x * 32;
  int tx = threadIdx.x & 31, ty = threadIdx.x >> 5;
#pragma unroll
  for (int i = 0; i < 4; i++)
    tile[ty + i*8][tx] = x[((size_t)b*DM + cB + ty + i*8)*NSEQ + nB + tx];
  __syncthreads();
#pragma unroll
  for (int i = 0; i < 4; i++) {
    float v = tile[tx][ty + i*8];
    size_t row = (size_t)b*NSEQ + nB + ty + i*8;
    xT [row*DM + cB + tx] = v;
    xbf[row*DM + cB + tx] = f2bf(v);
  }
}

// ---------------------------------------------------------------- weight convert
__global__ __launch_bounds__(256) void wconv_k(const float* __restrict__ wq,
    const float* __restrict__ wk, const float* __restrict__ wv,
    unsigned short* __restrict__ wbf) {
  int pj = blockIdx.y;
  const float* src = (pj == 0) ? wq : (pj == 1) ? wk : wv;
  int i = (blockIdx.x * 256 + threadIdx.x) * 4;
  float4 v = *(const float4*)(src + i);
  ushort4 o;
  o.x = f2bf(v.x); o.y = f2bf(v.y); o.z = f2bf(v.z); o.w = f2bf(v.w);
  *(ushort4*)(wbf + (size_t)pj*DM*DM + i) = o;
}

// ---------------------------------------------------------------- MFMA projections
// Q,K -> bf16 [b][h][n][d];  V -> fp16 transposed VT [b][h][d][n].
__global__ __launch_bounds__(256) void proj_mfma_k(
    const unsigned short* __restrict__ xbf,   // [NTOK][DM]
    const unsigned short* __restrict__ wbf,   // [3][DM][DM]
    const float* __restrict__ bq, const float* __restrict__ bk, const float* __restrict__ bv,
    unsigned short* __restrict__ Qo, unsigned short* __restrict__ Ko,
    unsigned short* __restrict__ VTo) {      // VT stored as f16 bit-pattern
  int tid = threadIdx.x, lane = tid & 63, w = tid >> 6;
  int g = lane >> 4, li = lane & 15;
  int wr = w >> 1, wc = w & 1;
  int h  = blockIdx.y;
  int pj = blockIdx.z;
  const unsigned short* wp0 = wbf + (size_t)pj * DM * DM;
  const float* bias = (pj == 0) ? bq : (pj == 1) ? bk : bv;

  const unsigned short *Am, *Bn;
  int mB, nB;
  if (pj < 2) { Am = wp0; mB = h*128 + wr*64;          Bn = xbf; nB = blockIdx.x*128 + wc*64; }
  else        { Am = xbf; mB = blockIdx.x*128 + wr*64; Bn = wp0; nB = h*128 + wc*64; }

  f32x4 acc[4][4];
#pragma unroll
  for (int fi = 0; fi < 4; fi++)
#pragma unroll
    for (int fj = 0; fj < 4; fj++) acc[fi][fj] = (f32x4){0.f, 0.f, 0.f, 0.f};

#pragma unroll 2
  for (int ks = 0; ks < DM/32; ks++) {
    bf16x8 af[4], bf[4];
#pragma unroll
    for (int fi = 0; fi < 4; fi++)
      af[fi] = *(const bf16x8*)(Am + (size_t)(mB + fi*16 + li)*DM + ks*32 + g*8);
#pragma unroll
    for (int fj = 0; fj < 4; fj++)
      bf[fj] = *(const bf16x8*)(Bn + (size_t)(nB + fj*16 + li)*DM + ks*32 + g*8);
#pragma unroll
    for (int fi = 0; fi < 4; fi++)
#pragma unroll
      for (int fj = 0; fj < 4; fj++)
        acc[fi][fj] = __builtin_amdgcn_mfma_f32_16x16x32_bf16(af[fi], bf[fj], acc[fi][fj], 0, 0, 0);
  }

  if (pj < 2) {
    unsigned short* dst = (pj == 0) ? Qo : Ko;
#pragma unroll
    for (int fi = 0; fi < 4; fi++) {
      int o0 = mB + fi*16 + g*4;
      float4 bb = *(const float4*)(bias + o0);
      int d0 = o0 & 127;
#pragma unroll
      for (int fj = 0; fj < 4; fj++) {
        int tok = nB + fj*16 + li;
        int bb_ = tok >> 11, n = tok & 2047;
        ushort4 v4;
        v4.x = f2bf(acc[fi][fj][0] + bb.x);
        v4.y = f2bf(acc[fi][fj][1] + bb.y);
        v4.z = f2bf(acc[fi][fj][2] + bb.z);
        v4.w = f2bf(acc[fi][fj][3] + bb.w);
        *(ushort4*)(dst + ((size_t)(bb_*NH + h)*NSEQ + n)*DK + d0) = v4;
      }
    }
  } else {
#pragma unroll
    for (int fj = 0; fj < 4; fj++) {
      int o  = nB + fj*16 + li;
      float bb = bias[o];
      int d  = o & 127;
#pragma unroll
      for (int fi = 0; fi < 4; fi++) {
        int tok0 = mB + fi*16 + g*4;
        int bb_ = tok0 >> 11, n0 = tok0 & 2047;
        ushort4 v4;
        v4.x = __builtin_bit_cast(unsigned short, (_Float16)(acc[fi][fj][0] + bb));
        v4.y = __builtin_bit_cast(unsigned short, (_Float16)(acc[fi][fj][1] + bb));
        v4.z = __builtin_bit_cast(unsigned short, (_Float16)(acc[fi][fj][2] + bb));
        v4.w = __builtin_bit_cast(unsigned short, (_Float16)(acc[fi][fj][3] + bb));
        *(ushort4*)(VTo + ((size_t)(bb_*NH + h)*DK + d)*NSEQ + n0) = v4;
      }
    }
  }
}

// ---------------------------------------------------------------- K1: z = QK^T
// Swapped operands: A = K rows (m = k-index), B = Q rows (n = q-index) so each
// lane's 4 acc regs are 4 consecutive k at fixed q -> ushort4 into z[q][k].
__global__ __launch_bounds__(256) void qk_k(const unsigned short* __restrict__ Qb,
    const unsigned short* __restrict__ Kb, _Float16* __restrict__ Z) {
  int tid = threadIdx.x, lane = tid & 63, w = tid >> 6;
  int g = lane >> 4, li = lane & 15;
  int wr = w >> 1, wc = w & 1;
  int kt = blockIdx.x, qt = blockIdx.y, bh = blockIdx.z;
  const unsigned short* Qh = Qb + (size_t)bh * NSEQ * DK;
  const unsigned short* Kh = Kb + (size_t)bh * NSEQ * DK;
  _Float16* Zh = Z + (size_t)bh * NSEQ * NSEQ;
  int kB = kt*128 + wr*64, qB = qt*128 + wc*64;
  const float zs = 0.044194173824159216f;   // 0.5 / sqrt(128)

  f32x4 acc[4][4];
#pragma unroll
  for (int fi = 0; fi < 4; fi++)
#pragma unroll
    for (int fj = 0; fj < 4; fj++) acc[fi][fj] = (f32x4){0.f, 0.f, 0.f, 0.f};

#pragma unroll
  for (int ks = 0; ks < 4; ks++) {
    bf16x8 af[4], bf[4];
#pragma unroll
    for (int fi = 0; fi < 4; fi++)
      af[fi] = *(const bf16x8*)(Kh + (size_t)(kB + fi*16 + li)*DK + ks*32 + g*8);
#pragma unroll
    for (int fj = 0; fj < 4; fj++)
      bf[fj] = *(const bf16x8*)(Qh + (size_t)(qB + fj*16 + li)*DK + ks*32 + g*8);
#pragma unroll
    for (int fi = 0; fi < 4; fi++)
#pragma unroll
      for (int fj = 0; fj < 4; fj++)
        acc[fi][fj] = __builtin_amdgcn_mfma_f32_16x16x32_bf16(af[fi], bf[fj], acc[fi][fj], 0, 0, 0);
  }

#pragma unroll
  for (int fj = 0; fj < 4; fj++) {
    int q = qB + fj*16 + li;
#pragma unroll
    for (int fi = 0; fi < 4; fi++) {
      int k0 = kB + fi*16 + g*4;
      ushort4 v4;
      v4.x = __builtin_bit_cast(unsigned short, (_Float16)(acc[fi][fj][0] * zs));
      v4.y = __builtin_bit_cast(unsigned short, (_Float16)(acc[fi][fj][1] * zs));
      v4.z = __builtin_bit_cast(unsigned short, (_Float16)(acc[fi][fj][2] * zs));
      v4.w = __builtin_bit_cast(unsigned short, (_Float16)(acc[fi][fj][3] * zs));
      *(ushort4*)(Zh + (size_t)q*NSEQ + k0) = v4;
    }
  }
}

// ---------------------------------------------------------------- entmax helpers
__device__ __forceinline__ void scan_row(const h2v* zh, float tau,
                                         float& f, float& g, float& c) {
  float ff = 0.f, gg = 0.f, cc = 0.f;
#if HAVE_FDOT2
  _Float16 th = (_Float16)tau;
  h2v t2 = {th, th};
  h2v zero2 = {(_Float16)0.f, (_Float16)0.f};
  h2v one2  = {(_Float16)1.f, (_Float16)1.f};
  h2v big2  = {(_Float16)60000.f, (_Float16)60000.f};
#pragma unroll
  for (int i = 0; i < 16; i++) {
    h2v d = __builtin_elementwise_max(zh[i] - t2, zero2);
    ff = __builtin_amdgcn_fdot2(d, d, ff, false);
    gg = __builtin_amdgcn_fdot2(d, one2, gg, false);
    h2v mm = __builtin_elementwise_min(d * big2, one2);
    cc = __builtin_amdgcn_fdot2(mm, one2, cc, false);
  }
#else
#pragma unroll
  for (int i = 0; i < 16; i++) {
#pragma unroll
    for (int j = 0; j < 2; j++) {
      float z = (float)zh[i][j];
      float d = fmaxf(z - tau, 0.f);
      ff = fmaf(d, d, ff);
      gg += d;
      cc += (d > 0.f) ? 1.f : 0.f;
    }
  }
#endif
  f = ff; g = gg; c = cc;
}

// frozen-support exact solve (Michelot step); Newton-back if overshot
__device__ __forceinline__ float nstep(float tau, float f, float g, float c, float m) {
  float num  = f - 1.0f;
  float disc = fmaxf(g*g - c*num, 0.f);
  float den  = (num >= 0.f) ? (g + sqrtf(disc)) : (2.0f * g);
  float t = tau + num / fmaxf(den, 1e-12f);
  return fminf(t, m - 0.01f);    // tau* <= m - 1/sqrt(2048); keeps support >= 1
}

// ---------------------------------------------------------------- K2: tau per row
__global__ __launch_bounds__(256) void tau_k(const _Float16* __restrict__ Z,
                                             float* __restrict__ tau) {
  int lane = threadIdx.x & 63, w = threadIdx.x >> 6;
  size_t rA = (size_t)blockIdx.x * 8 + w*2, rB = rA + 1;
  union { h8 v[4]; h2v h[16]; } ua, ub;
#pragma unroll
  for (int i = 0; i < 4; i++) {
    ua.v[i] = *(const h8*)(Z + rA*NSEQ + i*512 + lane*8);
    ub.v[i] = *(const h8*)(Z + rB*NSEQ + i*512 + lane*8);
  }
  h2v mxa = ua.h[0], mxb = ub.h[0];
#pragma unroll
  for (int i = 1; i < 16; i++) {
    mxa = __builtin_elementwise_max(mxa, ua.h[i]);
    mxb = __builtin_elementwise_max(mxb, ub.h[i]);
  }
  float mA = fmaxf((float)mxa[0], (float)mxa[1]);
  float mB = fmaxf((float)mxb[0], (float)mxb[1]);
#pragma unroll
  for (int off = 32; off > 0; off >>= 1) {
    mA = fmaxf(mA, __shfl_xor(mA, off));
    mB = fmaxf(mB, __shfl_xor(mB, off));
  }
  float tauA = mA - 1.0f, tauB = mB - 1.0f;
  for (int it = 0; it < NEWTON_IT; ++it) {
    float fA, gA, cA, fB, gB, cB;
    scan_row(ua.h, tauA, fA, gA, cA);
    scan_row(ub.h, tauB, fB, gB, cB);
#pragma unroll
    for (int off = 32; off > 0; off >>= 1) {
      fA += __shfl_xor(fA, off); gA += __shfl_xor(gA, off); cA += __shfl_xor(cA, off);
      fB += __shfl_xor(fB, off); gB += __shfl_xor(gB, off); cB += __shfl_xor(cB, off);
    }
    tauA = nstep(tauA, fA, gA, cA, mA);
    tauB = nstep(tauB, fB, gB, cB, mB);
  }
  if (lane == 0) { tau[rA] = tauA; tau[rB] = tauB; }
}

// ---------------------------------------------------------------- K3: O = P.V
// k-split across blockIdx.y (each half writes its own partial buffer) and
// software-pipelined (explicit next-chunk prefetch registers). No LDS/barriers.
// Grid (128 qtile, KSPLIT, 6 bh), block 256 (4 waves; wave w owns d [w*32,+32)).
__global__ __launch_bounds__(256) void pv_k(const _Float16* __restrict__ Z,
    const float* __restrict__ tau, const _Float16* __restrict__ VTb,
    float* __restrict__ AO0, float* __restrict__ AO1) {
  int tid = threadIdx.x, lane = tid & 63, w = tid >> 6;
  int g = lane >> 4, li = lane & 15;
  int qbase = blockIdx.x * 16, ks = blockIdx.y, bh = blockIdx.z;
  const _Float16* Zh  = Z   + ((size_t)bh * NSEQ + qbase) * NSEQ + (size_t)ks * KHALF;
  const _Float16* VTh = VTb + (size_t)bh * DK * NSEQ + (size_t)ks * KHALF;
  float* AO = ks ? AO1 : AO0;

  float tli = tau[(size_t)bh * NSEQ + qbase + li];
  _Float16 th = (_Float16)tli;
  h2v t2 = {th, th};
  h2v zero2 = {(_Float16)0.f, (_Float16)0.f};

  const _Float16* zrow  = Zh  + (size_t)li * NSEQ + g*8;          // A rows: q = li
  const _Float16* v0row = VTh + (size_t)(w*32 + li) * NSEQ + g*8; // B rows: d
  const _Float16* v1row = VTh + (size_t)(w*32 + 16 + li) * NSEQ + g*8;

  f32x4 acc0 = (f32x4){0.f,0.f,0.f,0.f}, acc1 = (f32x4){0.f,0.f,0.f,0.f};

  // prologue loads (chunk kc=0: two 32-k subchunks each)
  h8 za  = *(const h8*)(zrow);
  h8 zb  = *(const h8*)(zrow  + 32);
  h8 va0 = *(const h8*)(v0row);
  h8 vb0 = *(const h8*)(v0row + 32);
  h8 va1 = *(const h8*)(v1row);
  h8 vb1 = *(const h8*)(v1row + 32);

#define PV_BODY()                                                        \
  do {                                                                   \
    union { h8 v; h2v h[4]; } ua, ub;                                    \
    ua.v = za; ub.v = zb;                                                \
    _Pragma("unroll")                                                    \
    for (int j = 0; j < 4; j++) {                                        \
      h2v d0 = __builtin_elementwise_max(ua.h[j] - t2, zero2);           \
      ua.h[j] = d0 * d0;                                                 \
      h2v d1 = __builtin_elementwise_max(ub.h[j] - t2, zero2);           \
      ub.h[j] = d1 * d1;                                                 \
    }                                                                    \
    acc0 = __builtin_amdgcn_mfma_f32_16x16x32_f16(ua.v, va0, acc0, 0,0,0); \
    acc0 = __builtin_amdgcn_mfma_f32_16x16x32_f16(ub.v, vb0, acc0, 0,0,0); \
    acc1 = __builtin_amdgcn_mfma_f32_16x16x32_f16(ua.v, va1, acc1, 0,0,0); \
    acc1 = __builtin_amdgcn_mfma_f32_16x16x32_f16(ub.v, vb1, acc1, 0,0,0); \
  } while (0)

  for (int kc = 64; kc < KHALF; kc += 64) {
    // prefetch next chunk before consuming current
    h8 nza  = *(const h8*)(zrow  + kc);
    h8 nzb  = *(const h8*)(zrow  + kc + 32);
    h8 nva0 = *(const h8*)(v0row + kc);
    h8 nvb0 = *(const h8*)(v0row + kc + 32);
    h8 nva1 = *(const h8*)(v1row + kc);
    h8 nvb1 = *(const h8*)(v1row + kc + 32);
    PV_BODY();
    za = nza; zb = nzb; va0 = nva0; vb0 = nvb0; va1 = nva1; vb1 = nvb1;
  }
  PV_BODY();   // epilogue (last chunk, no prefetch)
#undef PV_BODY

  int b = bh / NH, h = bh % NH;
#pragma unroll
  for (int r = 0; r < 4; r++) {
    size_t rowo = ((size_t)b*NSEQ + qbase + g*4 + r)*DM + h*DK + w*32;
    AO[rowo + li]      = acc0[r];
    AO[rowo + 16 + li] = acc1[r];
  }
}

// ---------------------------------------------------------------- LN + residual
// out = x + LN(AO0 + AO1)
__global__ __launch_bounds__(256) void ln_k(const float* __restrict__ AO0,
    const float* __restrict__ AO1, const float* __restrict__ xT,
    const float* __restrict__ ga, const float* __restrict__ gb,
    float* __restrict__ outp) {
  int lane = threadIdx.x & 63;
  int wave = threadIdx.x >> 6;
  int row  = blockIdx.x * 4 + wave;
  const float* a0 = AO0 + (size_t)row*DM;
  const float* a1 = AO1 + (size_t)row*DM;
  float2 c0, c1, c2;
  {
    float2 p0 = *(const float2*)(a0 + lane*2),       q0 = *(const float2*)(a1 + lane*2);
    float2 p1 = *(const float2*)(a0 + 128 + lane*2), q1 = *(const float2*)(a1 + 128 + lane*2);
    float2 p2 = *(const float2*)(a0 + 256 + lane*2), q2 = *(const float2*)(a1 + 256 + lane*2);
    c0 = make_float2(p0.x + q0.x, p0.y + q0.y);
    c1 = make_float2(p1.x + q1.x, p1.y + q1.y);
    c2 = make_float2(p2.x + q2.x, p2.y + q2.y);
  }
  float s  = c0.x + c0.y + c1.x + c1.y + c2.x + c2.y;
  float ss = c0.x*c0.x + c0.y*c0.y + c1.x*c1.x + c1.y*c1.y + c2.x*c2.x + c2.y*c2.y;
#pragma unroll
  for (int off = 32; off > 0; off >>= 1) {
    s  += __shfl_xor(s,  off);
    ss += __shfl_xor(ss, off);
  }
  float mean = s * (1.0f / 384.0f);
  float var  = (ss - 384.0f*mean*mean) * (1.0f / 383.0f);   // Bessel (n-1)
  var = fmaxf(var, 0.f);
  float inv = 1.0f / (sqrtf(var) + 1e-6f);                  // eps added to STD
  const float* xr = xT + (size_t)row*DM;
  float* op = outp + (size_t)row*DM;
#pragma unroll
  for (int ch = 0; ch < 3; ch++) {
    int i0 = ch*128 + lane*2;
    float2 g  = *(const float2*)(ga + i0);
    float2 bb = *(const float2*)(gb + i0);
    float2 xv = *(const float2*)(xr + i0);
    float2 av = (ch == 0) ? c0 : (ch == 1) ? c1 : c2;
    float2 o;
    o.x = g.x*(av.x - mean)*inv + bb.x + xv.x;
    o.y = g.y*(av.y - mean)*inv + bb.y + xv.y;
    *(float2*)(op + i0) = o;
  }
}

// ---------------------------------------------------------------- launch
extern "C" void kernel_launch(void* const* d_in, const int* in_sizes, int n_in,
                              void* d_out, int out_size, void* d_ws, size_t ws_size,
                              hipStream_t stream) {
  const float* x  = (const float*)d_in[0];
  const float* wq = (const float*)d_in[1];
  const float* bq = (const float*)d_in[2];
  const float* wk = (const float*)d_in[3];
  const float* bk = (const float*)d_in[4];
  const float* wv = (const float*)d_in[5];
  const float* bv = (const float*)d_in[6];
  const float* la = (const float*)d_in[7];
  const float* lb = (const float*)d_in[8];
  float* out = (float*)d_out;

  // ws: xT f32 | AO0 f32 | Qb bf16 | Kb bf16 | VT f16 | xbf bf16 | wbf bf16 | Z f16 | tau f32 | AO1 f32
  char* wsb = (char*)d_ws;
  float* xT  = (float*)wsb;
  float* AO0 = (float*)(wsb + (size_t)SEG*4);
  unsigned short* Qb  = (unsigned short*)(wsb + (size_t)SEG*8);
  unsigned short* Kb  = (unsigned short*)(wsb + (size_t)SEG*8 + (size_t)SEG*2);
  unsigned short* VT  = (unsigned short*)(wsb + (size_t)SEG*8 + (size_t)SEG*4);
  unsigned short* xbf = (unsigned short*)(wsb + (size_t)SEG*8 + (size_t)SEG*6);
  unsigned short* wbf = (unsigned short*)(wsb + (size_t)SEG*8 + (size_t)SEG*8);
  char* zb = wsb + (size_t)SEG*16 + (size_t)3*DM*DM*2;
  _Float16* Z    = (_Float16*)zb;                                  // 6*2048*2048*2 B
  char* tb = zb + (size_t)BATCH*NH*NSEQ*NSEQ*2;
  float* taub = (float*)tb;                                        // 12288 f32
  float* AO1  = (float*)(tb + 65536);

  hipLaunchKernelGGL(transpose_k, dim3(NSEQ/32, DM/32, BATCH), dim3(256), 0, stream,
                     x, xT, xbf);
  hipLaunchKernelGGL(wconv_k, dim3(DM*DM/1024, 3), dim3(256), 0, stream, wq, wk, wv, wbf);
  hipLaunchKernelGGL(proj_mfma_k, dim3(NTOK/128, NH, 3), dim3(256), 0, stream,
                     xbf, wbf, bq, bk, bv, Qb, Kb, VT);
  hipLaunchKernelGGL(qk_k, dim3(NSEQ/128, NSEQ/128, BATCH*NH), dim3(256), 0, stream,
                     Qb, Kb, Z);
  hipLaunchKernelGGL(tau_k, dim3(BATCH*NH*NSEQ/8), dim3(256), 0, stream, Z, taub);
  hipLaunchKernelGGL(pv_k, dim3(NSEQ/16, KSPLIT, BATCH*NH), dim3(256), 0, stream,
                     Z, taub, (const _Float16*)VT, AO0, AO1);
  hipLaunchKernelGGL(ln_k, dim3(BATCH*NSEQ/4), dim3(256), 0, stream,
                     AO0, AO1, xT, la, lb, out);
}

// Round 7
// 142.455 us; speedup vs baseline: 1.2663x; 1.2663x over previous
//
#include <hip/hip_runtime.h>
#include <hip/hip_fp16.h>
#include <math.h>

// HieraFormer fused block:
//   transpose -> MFMA QKV proj -> fused attn (chunked MFMA QK^T -> reg-resident
//   fp16 z -> wave-local quadratic Newton -> chunked MFMA PV) -> LN+residual.
// B=2, D_MODEL=384, H=3, D_K=128, N=2048.
#define DM   384
#define NH   3
#define DK   128
#define NSEQ 2048
#define BATCH 2
#define NTOK (BATCH*NSEQ)      // 4096
#define SEG  (BATCH*NSEQ*DM)   // 1572864 elements
#define NEWTON_IT 8
#define ZP   520               // LDS chunk pitch in halves (512 + 8)

typedef __attribute__((ext_vector_type(8))) short     bf16x8;
typedef __attribute__((ext_vector_type(4))) float     f32x4;
typedef __attribute__((ext_vector_type(8))) _Float16  h8;
typedef __attribute__((ext_vector_type(2))) _Float16  h2v;

#if __has_builtin(__builtin_amdgcn_fdot2)
#define HAVE_FDOT2 1
#else
#define HAVE_FDOT2 0
#endif

__device__ __forceinline__ unsigned short f2bf(float f) {
  unsigned u = __builtin_bit_cast(unsigned, f);
  u += 0x7FFFu + ((u >> 16) & 1u);          // RNE
  return (unsigned short)(u >> 16);
}

// ---------------------------------------------------------------- transpose
__global__ __launch_bounds__(256) void transpose_k(const float* __restrict__ x,
                                                   float* __restrict__ xT,
                                                   unsigned short* __restrict__ xbf) {
  __shared__ float tile[32][33];
  int b  = blockIdx.z;
  int cB = blockIdx.y * 32;
  int nB = blockIdx.x * 32;
  int tx = threadIdx.x & 31, ty = threadIdx.x >> 5;
#pragma unroll
  for (int i = 0; i < 4; i++)
    tile[ty + i*8][tx] = x[((size_t)b*DM + cB + ty + i*8)*NSEQ + nB + tx];
  __syncthreads();
#pragma unroll
  for (int i = 0; i < 4; i++) {
    float v = tile[tx][ty + i*8];
    size_t row = (size_t)b*NSEQ + nB + ty + i*8;
    xT [row*DM + cB + tx] = v;
    xbf[row*DM + cB + tx] = f2bf(v);
  }
}

// ---------------------------------------------------------------- weight convert
__global__ __launch_bounds__(256) void wconv_k(const float* __restrict__ wq,
    const float* __restrict__ wk, const float* __restrict__ wv,
    unsigned short* __restrict__ wbf) {
  int pj = blockIdx.y;
  const float* src = (pj == 0) ? wq : (pj == 1) ? wk : wv;
  int i = (blockIdx.x * 256 + threadIdx.x) * 4;
  float4 v = *(const float4*)(src + i);
  ushort4 o;
  o.x = f2bf(v.x); o.y = f2bf(v.y); o.z = f2bf(v.z); o.w = f2bf(v.w);
  *(ushort4*)(wbf + (size_t)pj*DM*DM + i) = o;
}

// ---------------------------------------------------------------- MFMA projections
// Q,K -> bf16 [b][h][n][d];  V -> fp16 transposed VT [b][h][d][n].
__global__ __launch_bounds__(256) void proj_mfma_k(
    const unsigned short* __restrict__ xbf,   // [NTOK][DM]
    const unsigned short* __restrict__ wbf,   // [3][DM][DM]
    const float* __restrict__ bq, const float* __restrict__ bk, const float* __restrict__ bv,
    unsigned short* __restrict__ Qo, unsigned short* __restrict__ Ko,
    unsigned short* __restrict__ VTo) {      // VT stored as f16 bit-pattern
  int tid = threadIdx.x, lane = tid & 63, w = tid >> 6;
  int g = lane >> 4, li = lane & 15;
  int wr = w >> 1, wc = w & 1;
  int h  = blockIdx.y;
  int pj = blockIdx.z;
  const unsigned short* wp0 = wbf + (size_t)pj * DM * DM;
  const float* bias = (pj == 0) ? bq : (pj == 1) ? bk : bv;

  const unsigned short *Am, *Bn;
  int mB, nB;
  if (pj < 2) { Am = wp0; mB = h*128 + wr*64;          Bn = xbf; nB = blockIdx.x*128 + wc*64; }
  else        { Am = xbf; mB = blockIdx.x*128 + wr*64; Bn = wp0; nB = h*128 + wc*64; }

  f32x4 acc[4][4];
#pragma unroll
  for (int fi = 0; fi < 4; fi++)
#pragma unroll
    for (int fj = 0; fj < 4; fj++) acc[fi][fj] = (f32x4){0.f, 0.f, 0.f, 0.f};

#pragma unroll 2
  for (int ks = 0; ks < DM/32; ks++) {
    bf16x8 af[4], bf[4];
#pragma unroll
    for (int fi = 0; fi < 4; fi++)
      af[fi] = *(const bf16x8*)(Am + (size_t)(mB + fi*16 + li)*DM + ks*32 + g*8);
#pragma unroll
    for (int fj = 0; fj < 4; fj++)
      bf[fj] = *(const bf16x8*)(Bn + (size_t)(nB + fj*16 + li)*DM + ks*32 + g*8);
#pragma unroll
    for (int fi = 0; fi < 4; fi++)
#pragma unroll
      for (int fj = 0; fj < 4; fj++)
        acc[fi][fj] = __builtin_amdgcn_mfma_f32_16x16x32_bf16(af[fi], bf[fj], acc[fi][fj], 0, 0, 0);
  }

  if (pj < 2) {
    unsigned short* dst = (pj == 0) ? Qo : Ko;
#pragma unroll
    for (int fi = 0; fi < 4; fi++) {
      int o0 = mB + fi*16 + g*4;
      float4 bb = *(const float4*)(bias + o0);
      int d0 = o0 & 127;
#pragma unroll
      for (int fj = 0; fj < 4; fj++) {
        int tok = nB + fj*16 + li;
        int bb_ = tok >> 11, n = tok & 2047;
        ushort4 v4;
        v4.x = f2bf(acc[fi][fj][0] + bb.x);
        v4.y = f2bf(acc[fi][fj][1] + bb.y);
        v4.z = f2bf(acc[fi][fj][2] + bb.z);
        v4.w = f2bf(acc[fi][fj][3] + bb.w);
        *(ushort4*)(dst + ((size_t)(bb_*NH + h)*NSEQ + n)*DK + d0) = v4;
      }
    }
  } else {
#pragma unroll
    for (int fj = 0; fj < 4; fj++) {
      int o  = nB + fj*16 + li;
      float bb = bias[o];
      int d  = o & 127;
#pragma unroll
      for (int fi = 0; fi < 4; fi++) {
        int tok0 = mB + fi*16 + g*4;
        int bb_ = tok0 >> 11, n0 = tok0 & 2047;
        ushort4 v4;
        v4.x = __builtin_bit_cast(unsigned short, (_Float16)(acc[fi][fj][0] + bb));
        v4.y = __builtin_bit_cast(unsigned short, (_Float16)(acc[fi][fj][1] + bb));
        v4.z = __builtin_bit_cast(unsigned short, (_Float16)(acc[fi][fj][2] + bb));
        v4.w = __builtin_bit_cast(unsigned short, (_Float16)(acc[fi][fj][3] + bb));
        *(ushort4*)(VTo + ((size_t)(bb_*NH + h)*DK + d)*NSEQ + n0) = v4;
      }
    }
  }
}

// ---------------------------------------------------------------- entmax helpers
// scan f=sum d^2, g=sum d, c=support count over 16 half2 (one row slice)
__device__ __forceinline__ void scan16(const h2v* zh, float tau,
                                       float& f, float& g, float& c) {
  float ff = 0.f, gg = 0.f, cc = 0.f;
#if HAVE_FDOT2
  _Float16 th = (_Float16)tau;
  h2v t2 = {th, th};
  h2v zero2 = {(_Float16)0.f, (_Float16)0.f};
  h2v one2  = {(_Float16)1.f, (_Float16)1.f};
  h2v big2  = {(_Float16)60000.f, (_Float16)60000.f};
#pragma unroll
  for (int i = 0; i < 16; i++) {
    h2v d = __builtin_elementwise_max(zh[i] - t2, zero2);
    ff = __builtin_amdgcn_fdot2(d, d, ff, false);
    gg = __builtin_amdgcn_fdot2(d, one2, gg, false);
    h2v mm = __builtin_elementwise_min(d * big2, one2);
    cc = __builtin_amdgcn_fdot2(mm, one2, cc, false);
  }
#else
#pragma unroll
  for (int i = 0; i < 16; i++) {
#pragma unroll
    for (int j = 0; j < 2; j++) {
      float z = (float)zh[i][j];
      float d = fmaxf(z - tau, 0.f);
      ff = fmaf(d, d, ff);
      gg += d;
      cc += (d > 0.f) ? 1.f : 0.f;
    }
  }
#endif
  f = ff; g = gg; c = cc;
}

// frozen-support exact solve (Michelot step); Newton-back if overshot
__device__ __forceinline__ float nstep(float tau, float f, float g, float c, float m) {
  float num  = f - 1.0f;
  float disc = fmaxf(g*g - c*num, 0.f);
  float den  = (num >= 0.f) ? (g + sqrtf(disc)) : (2.0f * g);
  float t = tau + num / fmaxf(den, 1e-12f);
  return fminf(t, m - 0.01f);    // tau* <= m - 1/sqrt(2048); keeps support >= 1
}

// ---------------------------------------------------------------- fused attention
// Block = 32 q-rows of one (b,h); 512 thr = 8 waves. k processed in 4 chunks of
// 512. z fp16 lives in REGISTERS (wave w owns rows w*4..w*4+3, 16 h8/row-chunk);
// LDS is a 32x520 fp16 staging tile reused for (a) MFMA-layout -> row-layout
// transpose of z, (b) P chunks for the PV MFMA. Newton is wave-local: no LDS,
// no barriers. XCD-swizzled blockIdx keeps each head's K/V in one XCD's L2.
__global__ __launch_bounds__(512, 4) void attn_k(const unsigned short* __restrict__ Qb,
    const unsigned short* __restrict__ Kb, const _Float16* __restrict__ VTb,
    float* __restrict__ AO) {
  __shared__ _Float16 zc[32 * ZP];     // 33280 B

  int tid = threadIdx.x, lane = tid & 63, w = tid >> 6;
  int g = lane >> 4, li = lane & 15;
  // bijective XCD swizzle: 384 blocks = 8 XCDs x 48; consecutive swz share a head
  int swz = (blockIdx.x & 7) * 48 + (blockIdx.x >> 3);
  int bh = swz / (NSEQ/32), qb = swz % (NSEQ/32);
  int qbase = qb * 32;
  const unsigned short* Qh  = Qb  + (size_t)bh * NSEQ * DK;
  const unsigned short* Kh  = Kb  + (size_t)bh * NSEQ * DK;
  const _Float16*       VTh = VTb + (size_t)bh * DK * NSEQ;
  const float zs = 0.044194173824159216f;   // 0.5 / sqrt(128)

  // Q A-frags: rows qbase + fi*16 + li, k-slice ks*32 + g*8 (persistent)
  bf16x8 aq[2][4];
#pragma unroll
  for (int fi = 0; fi < 2; fi++)
#pragma unroll
    for (int ks = 0; ks < 4; ks++)
      aq[fi][ks] = *(const bf16x8*)(Qh + (size_t)(qbase + fi*16 + li)*DK + ks*32 + g*8);

  // ---- Phase 1: QK^T in 4 chunks of 512 k; z -> regs via LDS transpose
  h8 zr[4][4];   // [row r][chunk c]; all indices compile-time (full unroll)
#pragma unroll
  for (int c = 0; c < 4; c++) {
#pragma unroll
    for (int kt = 0; kt < 4; kt++) {
      int krow = c*512 + w*64 + kt*16 + li;
      bf16x8 bk[4];
#pragma unroll
      for (int ks = 0; ks < 4; ks++)
        bk[ks] = *(const bf16x8*)(Kh + (size_t)krow*DK + ks*32 + g*8);
      f32x4 za0 = (f32x4){0.f,0.f,0.f,0.f};
      f32x4 za1 = (f32x4){0.f,0.f,0.f,0.f};
#pragma unroll
      for (int ks = 0; ks < 4; ks++) {
        za0 = __builtin_amdgcn_mfma_f32_16x16x32_bf16(aq[0][ks], bk[ks], za0, 0, 0, 0);
        za1 = __builtin_amdgcn_mfma_f32_16x16x32_bf16(aq[1][ks], bk[ks], za1, 0, 0, 0);
      }
      int col = w*64 + kt*16 + li;
#pragma unroll
      for (int r = 0; r < 4; r++) {
        zc[(g*4 + r)*ZP + col]      = (_Float16)(za0[r] * zs);
        zc[(16 + g*4 + r)*ZP + col] = (_Float16)(za1[r] * zs);
      }
    }
    __syncthreads();   // z chunk complete in LDS
#pragma unroll
    for (int r = 0; r < 4; r++)
      zr[r][c] = *(const h8*)(zc + (w*4 + r)*ZP + lane*8);
    __syncthreads();   // reads done; LDS free for next chunk
  }

  // ---- Phase 2: wave-local Newton on 4 rows (rows w*4..w*4+3)
  float tau[4], mx[4];
  {
    union { h8 v[4]; h2v h[16]; } u;
#pragma unroll
    for (int r = 0; r < 4; r++) {
#pragma unroll
      for (int c = 0; c < 4; c++) u.v[c] = zr[r][c];
      h2v m2 = u.h[0];
#pragma unroll
      for (int i = 1; i < 16; i++) m2 = __builtin_elementwise_max(m2, u.h[i]);
      float m = fmaxf((float)m2[0], (float)m2[1]);
#pragma unroll
      for (int off = 32; off > 0; off >>= 1) m = fmaxf(m, __shfl_xor(m, off));
      mx[r] = m;
      tau[r] = m - 1.0f;
    }
    for (int it = 0; it < NEWTON_IT; ++it) {
      float f[4], gg[4], cc[4];
#pragma unroll
      for (int r = 0; r < 4; r++) {
        union { h8 v[4]; h2v h[16]; } ur;
#pragma unroll
        for (int c = 0; c < 4; c++) ur.v[c] = zr[r][c];
        scan16(ur.h, tau[r], f[r], gg[r], cc[r]);
      }
#pragma unroll
      for (int off = 32; off > 0; off >>= 1) {
#pragma unroll
        for (int r = 0; r < 4; r++) {
          f[r]  += __shfl_xor(f[r],  off);
          gg[r] += __shfl_xor(gg[r], off);
          cc[r] += __shfl_xor(cc[r], off);
        }
      }
#pragma unroll
      for (int r = 0; r < 4; r++) tau[r] = nstep(tau[r], f[r], gg[r], cc[r], mx[r]);
    }
  }

  // ---- Phase 3: PV in 4 chunks. P rebuilt from zr -> LDS; MFMA vs V^T.
  f32x4 pacc[2];
  pacc[0] = (f32x4){0.f,0.f,0.f,0.f};
  pacc[1] = (f32x4){0.f,0.f,0.f,0.f};
  int d0 = w * 16;                       // wave owns d in [w*16, w*16+16)
#pragma unroll
  for (int c = 0; c < 4; c++) {
    // convert own rows' chunk to P (fp16) and stage
#pragma unroll
    for (int r = 0; r < 4; r++) {
      union { h8 v; h2v h[4]; } u;
      u.v = zr[r][c];
      _Float16 th = (_Float16)tau[r];
      h2v t2 = {th, th};
      h2v zero2 = {(_Float16)0.f, (_Float16)0.f};
#pragma unroll
      for (int j = 0; j < 4; j++) {
        h2v d = __builtin_elementwise_max(u.h[j] - t2, zero2);
        u.h[j] = d * d;
      }
      *(h8*)(zc + (w*4 + r)*ZP + lane*8) = u.v;
    }
    __syncthreads();   // P chunk staged
#pragma unroll
    for (int kk = 0; kk < 16; kk++) {
      h8 bv = *(const h8*)(VTh + (size_t)(d0 + li)*NSEQ + c*512 + kk*32 + g*8);
      h8 pa0 = *(const h8*)(zc + (size_t)li*ZP + kk*32 + g*8);
      h8 pa1 = *(const h8*)(zc + (size_t)(16 + li)*ZP + kk*32 + g*8);
      pacc[0] = __builtin_amdgcn_mfma_f32_16x16x32_f16(pa0, bv, pacc[0], 0, 0, 0);
      pacc[1] = __builtin_amdgcn_mfma_f32_16x16x32_f16(pa1, bv, pacc[1], 0, 0, 0);
    }
    __syncthreads();   // MFMA reads done; LDS free for next chunk
  }

  // ---- epilogue: out[q][d]; frag rows q = fi*16+g*4+r, col d = d0+li
  int b = bh / NH, h = bh % NH;
#pragma unroll
  for (int fi = 0; fi < 2; fi++)
#pragma unroll
    for (int r = 0; r < 4; r++)
      AO[((size_t)b*NSEQ + qbase + fi*16 + g*4 + r)*DM + h*DK + d0 + li] = pacc[fi][r];
}

// ---------------------------------------------------------------- LN + residual
__global__ __launch_bounds__(256) void ln_k(const float* __restrict__ AO,
    const float* __restrict__ xT, const float* __restrict__ ga,
    const float* __restrict__ gb, float* __restrict__ outp) {
  int lane = threadIdx.x & 63;
  int wave = threadIdx.x >> 6;
  int row  = blockIdx.x * 4 + wave;
  const float* ao = AO + (size_t)row*DM;
  float2 c0 = *(const float2*)(ao + lane*2);
  float2 c1 = *(const float2*)(ao + 128 + lane*2);
  float2 c2 = *(const float2*)(ao + 256 + lane*2);
  float s  = c0.x + c0.y + c1.x + c1.y + c2.x + c2.y;
  float ss = c0.x*c0.x + c0.y*c0.y + c1.x*c1.x + c1.y*c1.y + c2.x*c2.x + c2.y*c2.y;
#pragma unroll
  for (int off = 32; off > 0; off >>= 1) {
    s  += __shfl_xor(s,  off);
    ss += __shfl_xor(ss, off);
  }
  float mean = s * (1.0f / 384.0f);
  float var  = (ss - 384.0f*mean*mean) * (1.0f / 383.0f);   // Bessel (n-1)
  var = fmaxf(var, 0.f);
  float inv = 1.0f / (sqrtf(var) + 1e-6f);                  // eps added to STD
  const float* xr = xT + (size_t)row*DM;
  float* op = outp + (size_t)row*DM;
#pragma unroll
  for (int ch = 0; ch < 3; ch++) {
    int i0 = ch*128 + lane*2;
    float2 g  = *(const float2*)(ga + i0);
    float2 bb = *(const float2*)(gb + i0);
    float2 xv = *(const float2*)(xr + i0);
    float2 av = (ch == 0) ? c0 : (ch == 1) ? c1 : c2;
    float2 o;
    o.x = g.x*(av.x - mean)*inv + bb.x + xv.x;
    o.y = g.y*(av.y - mean)*inv + bb.y + xv.y;
    *(float2*)(op + i0) = o;
  }
}

// ---------------------------------------------------------------- launch
extern "C" void kernel_launch(void* const* d_in, const int* in_sizes, int n_in,
                              void* d_out, int out_size, void* d_ws, size_t ws_size,
                              hipStream_t stream) {
  const float* x  = (const float*)d_in[0];
  const float* wq = (const float*)d_in[1];
  const float* bq = (const float*)d_in[2];
  const float* wk = (const float*)d_in[3];
  const float* bk = (const float*)d_in[4];
  const float* wv = (const float*)d_in[5];
  const float* bv = (const float*)d_in[6];
  const float* la = (const float*)d_in[7];
  const float* lb = (const float*)d_in[8];
  float* out = (float*)d_out;

  // ws: xT f32 | AO f32 | Qb bf16 | Kb bf16 | VT f16 | xbf bf16 | wbf bf16
  char* wsb = (char*)d_ws;
  float* xT = (float*)wsb;
  float* AO = (float*)(wsb + (size_t)SEG*4);
  unsigned short* Qb  = (unsigned short*)(wsb + (size_t)SEG*8);
  unsigned short* Kb  = (unsigned short*)(wsb + (size_t)SEG*8 + (size_t)SEG*2);
  unsigned short* VT  = (unsigned short*)(wsb + (size_t)SEG*8 + (size_t)SEG*4);
  unsigned short* xbf = (unsigned short*)(wsb + (size_t)SEG*8 + (size_t)SEG*6);
  unsigned short* wbf = (unsigned short*)(wsb + (size_t)SEG*8 + (size_t)SEG*8);

  hipLaunchKernelGGL(transpose_k, dim3(NSEQ/32, DM/32, BATCH), dim3(256), 0, stream,
                     x, xT, xbf);
  hipLaunchKernelGGL(wconv_k, dim3(DM*DM/1024, 3), dim3(256), 0, stream, wq, wk, wv, wbf);
  hipLaunchKernelGGL(proj_mfma_k, dim3(NTOK/128, NH, 3), dim3(256), 0, stream,
                     xbf, wbf, bq, bk, bv, Qb, Kb, VT);
  hipLaunchKernelGGL(attn_k, dim3(BATCH*NH*(NSEQ/32)), dim3(512), 0, stream,
                     Qb, Kb, (const _Float16*)VT, AO);
  hipLaunchKernelGGL(ln_k, dim3(BATCH*NSEQ/4), dim3(256), 0, stream, AO, xT, la, lb, out);
}